// Round 1
// baseline (1243.425 us; speedup 1.0000x reference)
//
#include <hip/hip_runtime.h>

constexpr int C = 128;

__global__ void k_init_deg(float* __restrict__ deg, int n) {
  int i = blockIdx.x * blockDim.x + threadIdx.x;
  if (i < n) deg[i] = 1.0f;
}

__global__ void k_edge_deg(const int* __restrict__ dst, const float* __restrict__ ew,
                           float* __restrict__ deg, int e) {
  int i = blockIdx.x * blockDim.x + threadIdx.x;
  if (i < e) unsafeAtomicAdd(&deg[dst[i]], ew[i]);
}

__global__ void k_dinv(float* __restrict__ deg, int n) {
  int i = blockIdx.x * blockDim.x + threadIdx.x;
  if (i < n) deg[i] = fminf(1.0f / sqrtf(deg[i]), 10000.0f);
}

__global__ void k_norm(const int* __restrict__ src, const int* __restrict__ dst,
                       const float* __restrict__ ew, const float* __restrict__ d,
                       float* __restrict__ nrm, int e) {
  int i = blockIdx.x * blockDim.x + threadIdx.x;
  if (i < e) nrm[i] = d[src[i]] * ew[i] * d[dst[i]];
}

// agg[i][c] = h[i][c] * d[i]^2   (self-loop contribution; fully initializes agg)
__global__ void k_selfloop(const float* __restrict__ h, const float* __restrict__ d,
                           float* __restrict__ agg, int n) {
  int g = blockIdx.x * blockDim.x + threadIdx.x;   // n*32 threads, 4 ch each
  int row = g >> 5, cg = g & 31;
  if (row < n) {
    float dd = d[row]; dd *= dd;
    float4 hv = *(const float4*)(h + (size_t)row * C + cg * 4);
    float4 o = make_float4(hv.x * dd, hv.y * dd, hv.z * dd, hv.w * dd);
    *(float4*)(agg + (size_t)row * C + cg * 4) = o;
  }
}

__global__ void k_edge_agg(const int* __restrict__ src, const int* __restrict__ dst,
                           const float* __restrict__ nrm, const float* __restrict__ h,
                           float* agg, int e) {
  int g = blockIdx.x * blockDim.x + threadIdx.x;   // e*32 threads, 4 ch each
  int eid = g >> 5, cg = g & 31;
  if (eid < e) {
    float nm = nrm[eid];
    int s = src[eid], t = dst[eid];
    float4 hv = *(const float4*)(h + (size_t)s * C + cg * 4);
    float* ap = agg + (size_t)t * C + cg * 4;
    unsafeAtomicAdd(ap + 0, hv.x * nm);
    unsafeAtomicAdd(ap + 1, hv.y * nm);
    unsafeAtomicAdd(ap + 2, hv.z * nm);
    unsafeAtomicAdd(ap + 3, hv.w * nm);
  }
}

#define ROWS 16
#define PAD 129

// x = agg @ W^T + b + h ; LN ; exact GELU.  agg == out (block reads its own
// rows into LDS before overwriting them; row partition across blocks is disjoint).
__launch_bounds__(256, 2)
__global__ void k_gemm_ln_gelu(const float* agg, const float* __restrict__ h,
                               const float* __restrict__ W, const float* __restrict__ b,
                               const float* __restrict__ gamma, const float* __restrict__ beta,
                               float* out, int n) {
  __shared__ float Wl[C][PAD];     // 66 KB
  __shared__ float Al[ROWS][PAD];  // 8.25 KB
  const int tid = threadIdx.x;
  const int row0 = blockIdx.x * ROWS;

  // stage W (row-major [j][k]) into LDS
  for (int t = tid; t < C * C / 4; t += 256) {
    int f = t * 4;
    float4 w = *(const float4*)(W + f);
    int j = f >> 7, k = f & 127;
    Wl[j][k] = w.x; Wl[j][k + 1] = w.y; Wl[j][k + 2] = w.z; Wl[j][k + 3] = w.w;
  }
  // stage agg tile
  for (int t = tid; t < ROWS * C / 4; t += 256) {
    int f = t * 4;
    int r = f >> 7, k = f & 127;
    int rr = row0 + r; if (rr >= n) rr = n - 1;
    float4 a = *(const float4*)(agg + (size_t)rr * C + k);
    Al[r][k] = a.x; Al[r][k + 1] = a.y; Al[r][k + 2] = a.z; Al[r][k + 3] = a.w;
  }
  __syncthreads();

  const int r = tid >> 4;      // 0..15 : row within tile
  const int jg = tid & 15;     // 0..15 : column group; cols j = jg + 16*jj
  const int row = row0 + r;

  float acc[8];
  #pragma unroll
  for (int jj = 0; jj < 8; ++jj) acc[jj] = 0.f;

  #pragma unroll 8
  for (int k = 0; k < C; ++k) {
    float a = Al[r][k];
    #pragma unroll
    for (int jj = 0; jj < 8; ++jj) acc[jj] += a * Wl[jg + jj * 16][k];
  }

  if (row < n) {
    float s = 0.f, s2 = 0.f;
    #pragma unroll
    for (int jj = 0; jj < 8; ++jj) {
      int j = jg + jj * 16;
      acc[jj] += b[j] + h[(size_t)row * C + j];
      s  += acc[jj];
      s2 += acc[jj] * acc[jj];
    }
    #pragma unroll
    for (int m = 8; m >= 1; m >>= 1) {
      s  += __shfl_xor(s, m, 16);
      s2 += __shfl_xor(s2, m, 16);
    }
    float mean = s * (1.0f / C);
    float var  = s2 * (1.0f / C) - mean * mean;
    float rstd = rsqrtf(var + 1e-5f);
    #pragma unroll
    for (int jj = 0; jj < 8; ++jj) {
      int j = jg + jj * 16;
      float y = gamma[j] * ((acc[jj] - mean) * rstd) + beta[j];
      out[(size_t)row * C + j] = 0.5f * y * (1.0f + erff(y * 0.70710678118f));
    }
  }
}

extern "C" void kernel_launch(void* const* d_in, const int* in_sizes, int n_in,
                              void* d_out, int out_size, void* d_ws, size_t ws_size,
                              hipStream_t stream) {
  const float* h     = (const float*)d_in[0];
  const int*   ei    = (const int*)d_in[1];
  const float* ew    = (const float*)d_in[2];
  const float* W     = (const float*)d_in[3];
  const float* b     = (const float*)d_in[4];
  const float* gamma = (const float*)d_in[5];
  const float* beta  = (const float*)d_in[6];

  const int n = in_sizes[0] / C;
  const int e = in_sizes[2];
  const int* src = ei;
  const int* dst = ei + e;

  float* out = (float*)d_out;
  float* deg = (float*)d_ws;        // n floats (becomes d in-place)
  float* nrm = deg + n;             // e floats
  float* agg = out;                 // aggregate directly into the output buffer

  k_init_deg<<<(n + 255) / 256, 256, 0, stream>>>(deg, n);
  k_edge_deg<<<(e + 255) / 256, 256, 0, stream>>>(dst, ew, deg, e);
  k_dinv    <<<(n + 255) / 256, 256, 0, stream>>>(deg, n);
  k_norm    <<<(e + 255) / 256, 256, 0, stream>>>(src, dst, ew, deg, nrm, e);
  k_selfloop<<<(n * 32 + 255) / 256, 256, 0, stream>>>(h, deg, agg, n);

  long ethreads = (long)e * 32;
  k_edge_agg<<<(int)((ethreads + 255) / 256), 256, 0, stream>>>(src, dst, nrm, h, agg, e);

  k_gemm_ln_gelu<<<(n + ROWS - 1) / ROWS, 256, 0, stream>>>(agg, h, W, b, gamma, beta, out, n);
}

// Round 2
// 339.696 us; speedup vs baseline: 3.6604x; 3.6604x over previous
//
#include <hip/hip_runtime.h>

constexpr int C = 128;
#define SCAN_CHUNK 1024   // 256 threads x 4 items per scan block

// ---- phase A: degree + d = min(deg^-1/2, 1e4); also zero CSR counts ----
__global__ void k_init(float* __restrict__ deg, int* __restrict__ counts, int n) {
  int i = blockIdx.x * blockDim.x + threadIdx.x;
  if (i < n) { deg[i] = 1.0f; counts[i] = 0; }
}

__global__ void k_edge_deg(const int* __restrict__ dst, const float* __restrict__ ew,
                           float* __restrict__ deg, int* __restrict__ counts, int e) {
  int i = blockIdx.x * blockDim.x + threadIdx.x;
  if (i < e) {
    int t = dst[i];
    unsafeAtomicAdd(&deg[t], ew[i]);
    atomicAdd(&counts[t], 1);
  }
}

__global__ void k_dinv(float* __restrict__ deg, int n) {
  int i = blockIdx.x * blockDim.x + threadIdx.x;
  if (i < n) deg[i] = fminf(1.0f / sqrtf(deg[i]), 10000.0f);
}

// ---- phase B: exclusive scan of counts -> rowptr; cursor = rowptr copy ----
__global__ void k_scan1(const int* __restrict__ cnt, int* __restrict__ excl,
                        int* __restrict__ sums, int n) {
  __shared__ int l[256];
  const int t = threadIdx.x;
  const int base = blockIdx.x * SCAN_CHUNK + t * 4;
  int v0 = 0, v1 = 0, v2 = 0, v3 = 0;
  if (base + 0 < n) v0 = cnt[base + 0];
  if (base + 1 < n) v1 = cnt[base + 1];
  if (base + 2 < n) v2 = cnt[base + 2];
  if (base + 3 < n) v3 = cnt[base + 3];
  const int s = v0 + v1 + v2 + v3;
  l[t] = s; __syncthreads();
  for (int off = 1; off < 256; off <<= 1) {
    int x = 0;
    if (t >= off) x = l[t - off];
    __syncthreads();
    l[t] += x;
    __syncthreads();
  }
  int ex = l[t] - s;
  if (t == 255) sums[blockIdx.x] = l[t];
  if (base + 0 < n) excl[base + 0] = ex;  ex += v0;
  if (base + 1 < n) excl[base + 1] = ex;  ex += v1;
  if (base + 2 < n) excl[base + 2] = ex;  ex += v2;
  if (base + 3 < n) excl[base + 3] = ex;
}

__global__ void k_scan2(int* __restrict__ sums, int nb) {  // nb <= 256
  __shared__ int l[256];
  const int t = threadIdx.x;
  const int s = (t < nb) ? sums[t] : 0;
  l[t] = s; __syncthreads();
  for (int off = 1; off < 256; off <<= 1) {
    int x = 0;
    if (t >= off) x = l[t - off];
    __syncthreads();
    l[t] += x;
    __syncthreads();
  }
  if (t < nb) sums[t] = l[t] - s;
}

__global__ void k_scan3(int* __restrict__ rowptr, const int* __restrict__ sums,
                        int* __restrict__ cursor, int n, int e) {
  int i = blockIdx.x * blockDim.x + threadIdx.x;
  if (i < n) {
    int v = rowptr[i] + sums[i >> 10];
    rowptr[i] = v;
    cursor[i] = v;
  }
  if (i == 0) rowptr[n] = e;
}

__global__ void k_scatter(const int* __restrict__ src, const int* __restrict__ dst,
                          const float* __restrict__ ew, int* __restrict__ cursor,
                          int* __restrict__ src_s, float* __restrict__ ew_s, int e) {
  int i = blockIdx.x * blockDim.x + threadIdx.x;
  if (i < e) {
    int t = dst[i];
    int p = atomicAdd(&cursor[t], 1);
    src_s[p] = src[i];
    ew_s[p]  = ew[i];
  }
}

// ---- phase C: gather-aggregate, one 32-lane group per dst node ----
__global__ void k_gather_agg(const int* __restrict__ rowptr, const int* __restrict__ src_s,
                             const float* __restrict__ ew_s, const float* __restrict__ d,
                             const float* __restrict__ h, float* __restrict__ agg, int n) {
  int g = blockIdx.x * blockDim.x + threadIdx.x;
  int v = g >> 5, lane = g & 31;
  if (v >= n) return;
  const float dv = d[v];
  const float dd = dv * dv;
  float4 hv = *(const float4*)(h + (size_t)v * C + lane * 4);
  float4 acc = make_float4(hv.x * dd, hv.y * dd, hv.z * dd, hv.w * dd);
  const int beg = rowptr[v], end = rowptr[v + 1];
  for (int p = beg; p < end; ++p) {
    int s = src_s[p];
    float nm = d[s] * ew_s[p] * dv;
    float4 x = *(const float4*)(h + (size_t)s * C + lane * 4);
    acc.x += x.x * nm; acc.y += x.y * nm; acc.z += x.z * nm; acc.w += x.w * nm;
  }
  *(float4*)(agg + (size_t)v * C + lane * 4) = acc;
}

// ---- phase D: x = agg @ W^T + b + h ; LN ; exact GELU ----
#define ROWS 16
#define PAD 129

__launch_bounds__(256, 2)
__global__ void k_gemm_ln_gelu(const float* agg, const float* __restrict__ h,
                               const float* __restrict__ W, const float* __restrict__ b,
                               const float* __restrict__ gamma, const float* __restrict__ beta,
                               float* out, int n) {
  __shared__ float Wl[C][PAD];
  __shared__ float Al[ROWS][PAD];
  const int tid = threadIdx.x;
  const int row0 = blockIdx.x * ROWS;

  for (int t = tid; t < C * C / 4; t += 256) {
    int f = t * 4;
    float4 w = *(const float4*)(W + f);
    int j = f >> 7, k = f & 127;
    Wl[j][k] = w.x; Wl[j][k + 1] = w.y; Wl[j][k + 2] = w.z; Wl[j][k + 3] = w.w;
  }
  for (int t = tid; t < ROWS * C / 4; t += 256) {
    int f = t * 4;
    int r = f >> 7, k = f & 127;
    int rr = row0 + r; if (rr >= n) rr = n - 1;
    float4 a = *(const float4*)(agg + (size_t)rr * C + k);
    Al[r][k] = a.x; Al[r][k + 1] = a.y; Al[r][k + 2] = a.z; Al[r][k + 3] = a.w;
  }
  __syncthreads();

  const int r = tid >> 4;
  const int jg = tid & 15;
  const int row = row0 + r;

  float acc[8];
  #pragma unroll
  for (int jj = 0; jj < 8; ++jj) acc[jj] = 0.f;

  #pragma unroll 8
  for (int k = 0; k < C; ++k) {
    float a = Al[r][k];
    #pragma unroll
    for (int jj = 0; jj < 8; ++jj) acc[jj] += a * Wl[jg + jj * 16][k];
  }

  if (row < n) {
    float s = 0.f, s2 = 0.f;
    #pragma unroll
    for (int jj = 0; jj < 8; ++jj) {
      int j = jg + jj * 16;
      acc[jj] += b[j] + h[(size_t)row * C + j];
      s  += acc[jj];
      s2 += acc[jj] * acc[jj];
    }
    #pragma unroll
    for (int m = 8; m >= 1; m >>= 1) {
      s  += __shfl_xor(s, m, 16);
      s2 += __shfl_xor(s2, m, 16);
    }
    float mean = s * (1.0f / C);
    float var  = s2 * (1.0f / C) - mean * mean;
    float rstd = rsqrtf(var + 1e-5f);
    #pragma unroll
    for (int jj = 0; jj < 8; ++jj) {
      int j = jg + jj * 16;
      float y = gamma[j] * ((acc[jj] - mean) * rstd) + beta[j];
      out[(size_t)row * C + j] = 0.5f * y * (1.0f + erff(y * 0.70710678118f));
    }
  }
}

extern "C" void kernel_launch(void* const* d_in, const int* in_sizes, int n_in,
                              void* d_out, int out_size, void* d_ws, size_t ws_size,
                              hipStream_t stream) {
  const float* h     = (const float*)d_in[0];
  const int*   ei    = (const int*)d_in[1];
  const float* ew    = (const float*)d_in[2];
  const float* W     = (const float*)d_in[3];
  const float* b     = (const float*)d_in[4];
  const float* gamma = (const float*)d_in[5];
  const float* beta  = (const float*)d_in[6];

  const int n = in_sizes[0] / C;
  const int e = in_sizes[2];
  const int* src = ei;
  const int* dst = ei + e;

  float* out = (float*)d_out;

  // workspace layout
  float* deg   = (float*)d_ws;          // n
  int* counts  = (int*)(deg + n);       // n
  int* rowptr  = counts + n;            // n+1
  int* sums    = rowptr + (n + 1);      // <=256
  int* cursor  = sums + 256;            // n
  int* src_s   = cursor + n;            // e
  float* ew_s  = (float*)(src_s + e);   // e
  float* agg   = out;                   // aggregate directly into output buffer

  const int nb = (n + SCAN_CHUNK - 1) / SCAN_CHUNK;   // 98 blocks, <=256 supported

  k_init    <<<(n + 255) / 256, 256, 0, stream>>>(deg, counts, n);
  k_edge_deg<<<(e + 255) / 256, 256, 0, stream>>>(dst, ew, deg, counts, e);
  k_dinv    <<<(n + 255) / 256, 256, 0, stream>>>(deg, n);

  k_scan1   <<<nb, 256, 0, stream>>>(counts, rowptr, sums, n);
  k_scan2   <<<1, 256, 0, stream>>>(sums, nb);
  k_scan3   <<<(n + 255) / 256, 256, 0, stream>>>(rowptr, sums, cursor, n, e);
  k_scatter <<<(e + 255) / 256, 256, 0, stream>>>(src, dst, ew, cursor, src_s, ew_s, e);

  long gthreads = (long)n * 32;
  k_gather_agg<<<(int)((gthreads + 255) / 256), 256, 0, stream>>>(
      rowptr, src_s, ew_s, deg, h, agg, n);

  k_gemm_ln_gelu<<<(n + ROWS - 1) / ROWS, 256, 0, stream>>>(agg, h, W, b, gamma, beta, out, n);
}

// Round 3
// 258.129 us; speedup vs baseline: 4.8171x; 1.3160x over previous
//
#include <hip/hip_runtime.h>

constexpr int C = 128;
#define SCAN_CHUNK 1024   // 256 threads x 4 items per scan block

// ---- phase A: degree + d = min(deg^-1/2, 1e4); also zero CSR counts ----
__global__ void k_init(float* __restrict__ deg, int* __restrict__ counts, int n) {
  int i = blockIdx.x * blockDim.x + threadIdx.x;
  if (i < n) { deg[i] = 1.0f; counts[i] = 0; }
}

__global__ void k_edge_deg(const int* __restrict__ dst, const float* __restrict__ ew,
                           float* __restrict__ deg, int* __restrict__ counts, int e) {
  int i = blockIdx.x * blockDim.x + threadIdx.x;
  if (i < e) {
    int t = dst[i];
    unsafeAtomicAdd(&deg[t], ew[i]);
    atomicAdd(&counts[t], 1);
  }
}

__global__ void k_dinv(float* __restrict__ deg, int n) {
  int i = blockIdx.x * blockDim.x + threadIdx.x;
  if (i < n) deg[i] = fminf(1.0f / sqrtf(deg[i]), 10000.0f);
}

// ---- phase B: exclusive scan of counts -> rowptr; cursor = rowptr copy ----
__global__ void k_scan1(const int* __restrict__ cnt, int* __restrict__ excl,
                        int* __restrict__ sums, int n) {
  __shared__ int l[256];
  const int t = threadIdx.x;
  const int base = blockIdx.x * SCAN_CHUNK + t * 4;
  int v0 = 0, v1 = 0, v2 = 0, v3 = 0;
  if (base + 0 < n) v0 = cnt[base + 0];
  if (base + 1 < n) v1 = cnt[base + 1];
  if (base + 2 < n) v2 = cnt[base + 2];
  if (base + 3 < n) v3 = cnt[base + 3];
  const int s = v0 + v1 + v2 + v3;
  l[t] = s; __syncthreads();
  for (int off = 1; off < 256; off <<= 1) {
    int x = 0;
    if (t >= off) x = l[t - off];
    __syncthreads();
    l[t] += x;
    __syncthreads();
  }
  int ex = l[t] - s;
  if (t == 255) sums[blockIdx.x] = l[t];
  if (base + 0 < n) excl[base + 0] = ex;  ex += v0;
  if (base + 1 < n) excl[base + 1] = ex;  ex += v1;
  if (base + 2 < n) excl[base + 2] = ex;  ex += v2;
  if (base + 3 < n) excl[base + 3] = ex;
}

__global__ void k_scan2(int* __restrict__ sums, int nb) {  // nb <= 256
  __shared__ int l[256];
  const int t = threadIdx.x;
  const int s = (t < nb) ? sums[t] : 0;
  l[t] = s; __syncthreads();
  for (int off = 1; off < 256; off <<= 1) {
    int x = 0;
    if (t >= off) x = l[t - off];
    __syncthreads();
    l[t] += x;
    __syncthreads();
  }
  if (t < nb) sums[t] = l[t] - s;
}

__global__ void k_scan3(int* __restrict__ rowptr, const int* __restrict__ sums,
                        int* __restrict__ cursor, int n, int e) {
  int i = blockIdx.x * blockDim.x + threadIdx.x;
  if (i < n) {
    int v = rowptr[i] + sums[i >> 10];
    rowptr[i] = v;
    cursor[i] = v;
  }
  if (i == 0) rowptr[n] = e;
}

// scatter edges into dst-sorted order; fold the norm computation in here so the
// gather inner loop has no dependent d[] load.
__global__ void k_scatter(const int* __restrict__ src, const int* __restrict__ dst,
                          const float* __restrict__ ew, const float* __restrict__ d,
                          int* __restrict__ cursor, int2* __restrict__ meta, int e) {
  int i = blockIdx.x * blockDim.x + threadIdx.x;
  if (i < e) {
    int t = dst[i], s = src[i];
    float nm = d[s] * ew[i] * d[t];
    int p = atomicAdd(&cursor[t], 1);
    meta[p] = make_int2(s, __float_as_int(nm));
  }
}

// ---- phase C: gather-aggregate, one 32-lane group per dst node ----
__global__ void k_gather_agg(const int* __restrict__ rowptr, const int2* __restrict__ meta,
                             const float* __restrict__ d, const float* __restrict__ h,
                             float* __restrict__ agg, int n) {
  int g = blockIdx.x * blockDim.x + threadIdx.x;
  int v = g >> 5, lane = g & 31;
  if (v >= n) return;
  const float dv = d[v];
  const float dd = dv * dv;
  float4 hv = *(const float4*)(h + (size_t)v * C + lane * 4);
  float4 acc = make_float4(hv.x * dd, hv.y * dd, hv.z * dd, hv.w * dd);
  int p = rowptr[v];
  const int end = rowptr[v + 1];
  for (; p + 2 <= end; p += 2) {
    int2 m0 = meta[p], m1 = meta[p + 1];
    float n0 = __int_as_float(m0.y), n1 = __int_as_float(m1.y);
    float4 x0 = *(const float4*)(h + (size_t)m0.x * C + lane * 4);
    float4 x1 = *(const float4*)(h + (size_t)m1.x * C + lane * 4);
    acc.x += x0.x * n0 + x1.x * n1;
    acc.y += x0.y * n0 + x1.y * n1;
    acc.z += x0.z * n0 + x1.z * n1;
    acc.w += x0.w * n0 + x1.w * n1;
  }
  if (p < end) {
    int2 m0 = meta[p];
    float n0 = __int_as_float(m0.y);
    float4 x0 = *(const float4*)(h + (size_t)m0.x * C + lane * 4);
    acc.x += x0.x * n0; acc.y += x0.y * n0; acc.z += x0.z * n0; acc.w += x0.w * n0;
  }
  *(float4*)(agg + (size_t)v * C + lane * 4) = acc;
}

// ---- phase D: x = agg @ W^T + b + h ; LN ; exact GELU ----
// Persistent-ish: grid=GGRID blocks, each stages W once (XOR-swizzled, 64KB)
// and loops over 32-row chunks. 2 blocks/CU (80KB LDS each).
#define GROWS 32
#define GGRID 512

__launch_bounds__(256, 2)
__global__ void k_gemm_ln_gelu(const float* __restrict__ agg, const float* __restrict__ h,
                               const float* __restrict__ W, const float* __restrict__ b,
                               const float* __restrict__ gamma, const float* __restrict__ beta,
                               float* __restrict__ out, int n) {
  __shared__ float Wl[C * C];        // 64 KB, float4 units, XOR-swizzled
  __shared__ float Al[GROWS * C];    // 16 KB, float4 units, XOR-swizzled
  float4* Wl4 = (float4*)Wl;
  float4* Al4 = (float4*)Al;
  const int tid = threadIdx.x;

  // stage W: unit u -> row j = u>>5, quad k4 = u&31; swizzle k4 ^= (j&7)
  for (int u = tid; u < C * C / 4; u += 256) {
    int j = u >> 5, k4 = u & 31;
    Wl4[(j << 5) | (k4 ^ (j & 7))] = ((const float4*)W)[u];
  }

  const int jg = tid & 15;          // cols j = jg + 16*jj
  const int ty = tid >> 4;          // rows r0 = ty, r1 = ty + 16 (within chunk)

  // hoist per-column constants
  float bj[8], gj[8], btj[8];
  #pragma unroll
  for (int jj = 0; jj < 8; ++jj) {
    int j = jg + (jj << 4);
    bj[jj] = b[j]; gj[jj] = gamma[j]; btj[jj] = beta[j];
  }

  const int nchunks = (n + GROWS - 1) / GROWS;   // 3125 for n=100000 (exact)
  int c = blockIdx.x;
  float4 pre[4];
  if (c < nchunks) {
    #pragma unroll
    for (int i = 0; i < 4; ++i)
      pre[i] = ((const float4*)(agg + (size_t)c * GROWS * C))[tid + i * 256];
  }
  __syncthreads();   // W staged; Al not yet touched

  for (; c < nchunks; c += GGRID) {
    // write staged chunk into Al (swizzled)
    #pragma unroll
    for (int i = 0; i < 4; ++i) {
      int u = tid + i * 256;
      int r = u >> 5, k4 = u & 31;
      Al4[(r << 5) | (k4 ^ (r & 7))] = pre[i];
    }
    __syncthreads();

    // prefetch next chunk into registers while computing this one
    int cn = c + GGRID;
    if (cn < nchunks) {
      #pragma unroll
      for (int i = 0; i < 4; ++i)
        pre[i] = ((const float4*)(agg + (size_t)cn * GROWS * C))[tid + i * 256];
    }

    float acc0[8], acc1[8];
    #pragma unroll
    for (int jj = 0; jj < 8; ++jj) { acc0[jj] = 0.f; acc1[jj] = 0.f; }

    const int q0 = (ty) & 7, q1 = (ty + 16) & 7;
    #pragma unroll 4
    for (int k4 = 0; k4 < 32; ++k4) {
      float4 a0 = Al4[(ty << 5) | (k4 ^ q0)];
      float4 a1 = Al4[((ty + 16) << 5) | (k4 ^ q1)];
      #pragma unroll
      for (int jj = 0; jj < 8; ++jj) {
        int j = jg + (jj << 4);
        float4 w = Wl4[(j << 5) | (k4 ^ (j & 7))];
        acc0[jj] += a0.x * w.x + a0.y * w.y + a0.z * w.z + a0.w * w.w;
        acc1[jj] += a1.x * w.x + a1.y * w.y + a1.z * w.z + a1.w * w.w;
      }
    }

    // epilogue: + b + h, LN over 128 cols (16-lane shfl groups), GELU
    const int row0 = c * GROWS + ty;
    const int row1 = row0 + 16;
    const size_t rb0 = (size_t)row0 * C;
    const size_t rb1 = (size_t)row1 * C;
    const bool ok0 = row0 < n, ok1 = row1 < n;
    float s0 = 0.f, t0 = 0.f, s1 = 0.f, t1 = 0.f;
    #pragma unroll
    for (int jj = 0; jj < 8; ++jj) {
      int j = jg + (jj << 4);
      float x0 = acc0[jj] + bj[jj] + (ok0 ? h[rb0 + j] : 0.f);
      float x1 = acc1[jj] + bj[jj] + (ok1 ? h[rb1 + j] : 0.f);
      acc0[jj] = x0; acc1[jj] = x1;
      s0 += x0; t0 += x0 * x0;
      s1 += x1; t1 += x1 * x1;
    }
    #pragma unroll
    for (int m = 8; m >= 1; m >>= 1) {
      s0 += __shfl_xor(s0, m, 16); t0 += __shfl_xor(t0, m, 16);
      s1 += __shfl_xor(s1, m, 16); t1 += __shfl_xor(t1, m, 16);
    }
    const float inv = 1.0f / C;
    float mean0 = s0 * inv, var0 = t0 * inv - mean0 * mean0;
    float mean1 = s1 * inv, var1 = t1 * inv - mean1 * mean1;
    float rs0 = rsqrtf(var0 + 1e-5f), rs1 = rsqrtf(var1 + 1e-5f);
    #pragma unroll
    for (int jj = 0; jj < 8; ++jj) {
      int j = jg + (jj << 4);
      if (ok0) {
        float y = gj[jj] * ((acc0[jj] - mean0) * rs0) + btj[jj];
        out[rb0 + j] = 0.5f * y * (1.0f + erff(y * 0.70710678118f));
      }
      if (ok1) {
        float y = gj[jj] * ((acc1[jj] - mean1) * rs1) + btj[jj];
        out[rb1 + j] = 0.5f * y * (1.0f + erff(y * 0.70710678118f));
      }
    }
    __syncthreads();   // everyone done reading Al before next overwrite
  }
}

extern "C" void kernel_launch(void* const* d_in, const int* in_sizes, int n_in,
                              void* d_out, int out_size, void* d_ws, size_t ws_size,
                              hipStream_t stream) {
  const float* h     = (const float*)d_in[0];
  const int*   ei    = (const int*)d_in[1];
  const float* ew    = (const float*)d_in[2];
  const float* W     = (const float*)d_in[3];
  const float* b     = (const float*)d_in[4];
  const float* gamma = (const float*)d_in[5];
  const float* beta  = (const float*)d_in[6];

  const int n = in_sizes[0] / C;
  const int e = in_sizes[2];
  const int* src = ei;
  const int* dst = ei + e;

  float* out = (float*)d_out;

  // workspace layout (meta first for 8B alignment)
  int2* meta   = (int2*)d_ws;           // e int2
  float* deg   = (float*)(meta + e);    // n
  int* counts  = (int*)(deg + n);       // n
  int* rowptr  = counts + n;            // n+1
  int* sums    = rowptr + (n + 1);      // <=256
  int* cursor  = sums + 256;            // n
  float* agg   = out;                   // aggregate directly into output buffer

  const int nb = (n + SCAN_CHUNK - 1) / SCAN_CHUNK;

  k_init    <<<(n + 255) / 256, 256, 0, stream>>>(deg, counts, n);
  k_edge_deg<<<(e + 255) / 256, 256, 0, stream>>>(dst, ew, deg, counts, e);
  k_dinv    <<<(n + 255) / 256, 256, 0, stream>>>(deg, n);

  k_scan1   <<<nb, 256, 0, stream>>>(counts, rowptr, sums, n);
  k_scan2   <<<1, 256, 0, stream>>>(sums, nb);
  k_scan3   <<<(n + 255) / 256, 256, 0, stream>>>(rowptr, sums, cursor, n, e);
  k_scatter <<<(e + 255) / 256, 256, 0, stream>>>(src, dst, ew, deg, cursor, meta, e);

  long gthreads = (long)n * 32;
  k_gather_agg<<<(int)((gthreads + 255) / 256), 256, 0, stream>>>(
      rowptr, meta, deg, h, agg, n);

  k_gemm_ln_gelu<<<GGRID, 256, 0, stream>>>(agg, h, W, b, gamma, beta, out, n);
}

// Round 4
// 196.680 us; speedup vs baseline: 6.3221x; 1.3124x over previous
//
#include <hip/hip_runtime.h>

constexpr int C = 128;
#define SCAN_CHUNK 1024   // 256 threads x 4 items per scan block

typedef __attribute__((ext_vector_type(8))) short short8;   // 8 bf16 = 4 VGPR
typedef __attribute__((ext_vector_type(4))) float f32x4;

__device__ __forceinline__ unsigned short f2bf(float f) {   // RNE f32->bf16
  unsigned int u = __float_as_uint(f);
  unsigned int r = (u + 0x7fffu + ((u >> 16) & 1u)) >> 16;
  return (unsigned short)r;
}

// ---- phase 0: W f32 -> bf16 ----
__global__ void k_prep(const float* __restrict__ W, unsigned short* __restrict__ Wb) {
  int i = blockIdx.x * blockDim.x + threadIdx.x;   // 4096 float4 units
  float4 w = ((const float4*)W)[i];
  uint2 pk;
  pk.x = f2bf(w.x) | ((unsigned int)f2bf(w.y) << 16);
  pk.y = f2bf(w.z) | ((unsigned int)f2bf(w.w) << 16);
  ((uint2*)Wb)[i] = pk;
}

// ---- phase A: degree + d = min(deg^-1/2, 1e4); also zero CSR counts ----
__global__ void k_init(float* __restrict__ deg, int* __restrict__ counts, int n) {
  int i = blockIdx.x * blockDim.x + threadIdx.x;
  if (i < n) { deg[i] = 1.0f; counts[i] = 0; }
}

__global__ void k_edge_deg(const int* __restrict__ dst, const float* __restrict__ ew,
                           float* __restrict__ deg, int* __restrict__ counts, int e) {
  int i = blockIdx.x * blockDim.x + threadIdx.x;
  if (i < e) {
    int t = dst[i];
    unsafeAtomicAdd(&deg[t], ew[i]);
    atomicAdd(&counts[t], 1);
  }
}

__global__ void k_dinv(float* __restrict__ deg, int n) {
  int i = blockIdx.x * blockDim.x + threadIdx.x;
  if (i < n) deg[i] = fminf(1.0f / sqrtf(deg[i]), 10000.0f);
}

// ---- phase B: exclusive scan of counts -> rowptr; cursor = rowptr copy ----
__global__ void k_scan1(const int* __restrict__ cnt, int* __restrict__ excl,
                        int* __restrict__ sums, int n) {
  __shared__ int l[256];
  const int t = threadIdx.x;
  const int base = blockIdx.x * SCAN_CHUNK + t * 4;
  int v0 = 0, v1 = 0, v2 = 0, v3 = 0;
  if (base + 0 < n) v0 = cnt[base + 0];
  if (base + 1 < n) v1 = cnt[base + 1];
  if (base + 2 < n) v2 = cnt[base + 2];
  if (base + 3 < n) v3 = cnt[base + 3];
  const int s = v0 + v1 + v2 + v3;
  l[t] = s; __syncthreads();
  for (int off = 1; off < 256; off <<= 1) {
    int x = 0;
    if (t >= off) x = l[t - off];
    __syncthreads();
    l[t] += x;
    __syncthreads();
  }
  int ex = l[t] - s;
  if (t == 255) sums[blockIdx.x] = l[t];
  if (base + 0 < n) excl[base + 0] = ex;  ex += v0;
  if (base + 1 < n) excl[base + 1] = ex;  ex += v1;
  if (base + 2 < n) excl[base + 2] = ex;  ex += v2;
  if (base + 3 < n) excl[base + 3] = ex;
}

__global__ void k_scan2(int* __restrict__ sums, int nb) {  // nb <= 256
  __shared__ int l[256];
  const int t = threadIdx.x;
  const int s = (t < nb) ? sums[t] : 0;
  l[t] = s; __syncthreads();
  for (int off = 1; off < 256; off <<= 1) {
    int x = 0;
    if (t >= off) x = l[t - off];
    __syncthreads();
    l[t] += x;
    __syncthreads();
  }
  if (t < nb) sums[t] = l[t] - s;
}

__global__ void k_scan3(int* __restrict__ rowptr, const int* __restrict__ sums,
                        int* __restrict__ cursor, int n, int e) {
  int i = blockIdx.x * blockDim.x + threadIdx.x;
  if (i < n) {
    int v = rowptr[i] + sums[i >> 10];
    rowptr[i] = v;
    cursor[i] = v;
  }
  if (i == 0) rowptr[n] = e;
}

// scatter edges into dst-sorted order; norm folded in.
__global__ void k_scatter(const int* __restrict__ src, const int* __restrict__ dst,
                          const float* __restrict__ ew, const float* __restrict__ d,
                          int* __restrict__ cursor, int2* __restrict__ meta, int e) {
  int i = blockIdx.x * blockDim.x + threadIdx.x;
  if (i < e) {
    int t = dst[i], s = src[i];
    float nm = d[s] * ew[i] * d[t];
    int p = atomicAdd(&cursor[t], 1);
    meta[p] = make_int2(s, __float_as_int(nm));
  }
}

// ---- phase C: gather-aggregate, 32 lanes per dst node, unroll-4 for MLP ----
__global__ void k_gather_agg(const int* __restrict__ rowptr, const int2* __restrict__ meta,
                             const float* __restrict__ d, const float* __restrict__ h,
                             float* __restrict__ agg, int n) {
  int g = blockIdx.x * blockDim.x + threadIdx.x;
  int v = g >> 5, lane = g & 31;
  if (v >= n) return;
  const float dv = d[v];
  const float dd = dv * dv;
  float4 hv = *(const float4*)(h + (size_t)v * C + lane * 4);
  float4 acc = make_float4(hv.x * dd, hv.y * dd, hv.z * dd, hv.w * dd);
  int p = rowptr[v];
  const int end = rowptr[v + 1];
  for (; p + 4 <= end; p += 4) {
    int2 m0 = meta[p], m1 = meta[p + 1], m2 = meta[p + 2], m3 = meta[p + 3];
    float n0 = __int_as_float(m0.y), n1 = __int_as_float(m1.y);
    float n2 = __int_as_float(m2.y), n3 = __int_as_float(m3.y);
    float4 x0 = *(const float4*)(h + (size_t)m0.x * C + lane * 4);
    float4 x1 = *(const float4*)(h + (size_t)m1.x * C + lane * 4);
    float4 x2 = *(const float4*)(h + (size_t)m2.x * C + lane * 4);
    float4 x3 = *(const float4*)(h + (size_t)m3.x * C + lane * 4);
    acc.x += x0.x * n0 + x1.x * n1 + x2.x * n2 + x3.x * n3;
    acc.y += x0.y * n0 + x1.y * n1 + x2.y * n2 + x3.y * n3;
    acc.z += x0.z * n0 + x1.z * n1 + x2.z * n2 + x3.z * n3;
    acc.w += x0.w * n0 + x1.w * n1 + x2.w * n2 + x3.w * n3;
  }
  for (; p + 2 <= end; p += 2) {
    int2 m0 = meta[p], m1 = meta[p + 1];
    float n0 = __int_as_float(m0.y), n1 = __int_as_float(m1.y);
    float4 x0 = *(const float4*)(h + (size_t)m0.x * C + lane * 4);
    float4 x1 = *(const float4*)(h + (size_t)m1.x * C + lane * 4);
    acc.x += x0.x * n0 + x1.x * n1;
    acc.y += x0.y * n0 + x1.y * n1;
    acc.z += x0.z * n0 + x1.z * n1;
    acc.w += x0.w * n0 + x1.w * n1;
  }
  if (p < end) {
    int2 m0 = meta[p];
    float n0 = __int_as_float(m0.y);
    float4 x0 = *(const float4*)(h + (size_t)m0.x * C + lane * 4);
    acc.x += x0.x * n0; acc.y += x0.y * n0; acc.z += x0.z * n0; acc.w += x0.w * n0;
  }
  *(float4*)(agg + (size_t)v * C + lane * 4) = acc;
}

// ---- phase D: x = agg @ W^T + b + h ; LN ; exact GELU  (bf16 MFMA) ----
// One block = 64 rows, 4 waves x (16 rows x 128 cols). agg == out (in-place,
// block reads its own rows before overwriting; row partition disjoint).
#define TM 64

__launch_bounds__(256, 2)
__global__ void k_mfma_ln_gelu(const float* __restrict__ agg, const float* __restrict__ h,
                               const unsigned short* __restrict__ Wb,
                               const float* __restrict__ b,
                               const float* __restrict__ gamma, const float* __restrict__ beta,
                               float* __restrict__ out, int n) {
  __shared__ char lds[48 * 1024];
  char* Wl = lds;              // 32 KB bf16 [128][128], swizzled
  char* Al = lds + 32768;      // 16 KB bf16 [64][128],  swizzled
  const int tid = threadIdx.x;
  const int row0 = blockIdx.x * TM;

  // stage W (bf16, 2048 x 16B units), swizzle: byte ^= (row&7)<<4
  #pragma unroll
  for (int i = 0; i < 8; ++i) {
    int u = tid + i * 256;
    int j = u >> 4, un = u & 15;
    uint4 w = ((const uint4*)Wb)[u];
    *(uint4*)(Wl + j * 256 + ((un * 16) ^ ((j & 7) << 4))) = w;
  }
  // stage A tile: f32 -> bf16 RNE, swizzled (2048 float4 units)
  #pragma unroll
  for (int i = 0; i < 8; ++i) {
    int u = tid + i * 256;
    int j = u >> 5;                       // row in tile
    int rr = row0 + j; if (rr >= n) rr = n - 1;
    float4 a = ((const float4*)(agg + (size_t)rr * C))[u & 31];
    uint2 pk;
    pk.x = f2bf(a.x) | ((unsigned int)f2bf(a.y) << 16);
    pk.y = f2bf(a.z) | ((unsigned int)f2bf(a.w) << 16);
    *(uint2*)(Al + j * 256 + (((u & 31) * 8) ^ ((j & 7) << 4))) = pk;
  }
  __syncthreads();

  const int lane = tid & 63;
  const int wt   = tid >> 6;     // wave -> rows wt*16..+15
  const int c16  = lane & 15;
  const int quad = lane >> 4;

  f32x4 acc[8];
  #pragma unroll
  for (int jt = 0; jt < 8; ++jt) acc[jt] = (f32x4){0.f, 0.f, 0.f, 0.f};

  const int abase = (wt * 16 + c16) * 256;
  const int swz   = (c16 & 7) << 4;
  #pragma unroll
  for (int ks = 0; ks < 4; ++ks) {
    const int koff = ks * 64 + quad * 16;
    short8 af = *(const short8*)(Al + abase + (koff ^ swz));
    #pragma unroll
    for (int jt = 0; jt < 8; ++jt) {
      short8 bf = *(const short8*)(Wl + (jt * 16 + c16) * 256 + (koff ^ swz));
      acc[jt] = __builtin_amdgcn_mfma_f32_16x16x32_bf16(af, bf, acc[jt], 0, 0, 0);
    }
  }

  // epilogue: lane owns rows row0+wt*16+quad*4+i (i=0..3), cols jt*16+c16
  float bj[8], gj[8], btj[8];
  #pragma unroll
  for (int jt = 0; jt < 8; ++jt) {
    int j = jt * 16 + c16;
    bj[jt] = b[j]; gj[jt] = gamma[j]; btj[jt] = beta[j];
  }

  #pragma unroll
  for (int i = 0; i < 4; ++i) {
    const int row = row0 + wt * 16 + quad * 4 + i;
    const bool ok = row < n;
    const float* hrow = h + (size_t)row * C;
    float x[8];
    float s = 0.f, t2 = 0.f;
    #pragma unroll
    for (int jt = 0; jt < 8; ++jt) {
      float v = acc[jt][i] + bj[jt] + (ok ? hrow[jt * 16 + c16] : 0.f);
      x[jt] = v; s += v; t2 += v * v;
    }
    #pragma unroll
    for (int m = 8; m >= 1; m >>= 1) {
      s += __shfl_xor(s, m, 16); t2 += __shfl_xor(t2, m, 16);
    }
    const float inv = 1.0f / C;
    float mean = s * inv;
    float var  = t2 * inv - mean * mean;
    float rstd = rsqrtf(var + 1e-5f);
    if (ok) {
      float* orow = out + (size_t)row * C;
      #pragma unroll
      for (int jt = 0; jt < 8; ++jt) {
        float y = gj[jt] * ((x[jt] - mean) * rstd) + btj[jt];
        orow[jt * 16 + c16] = 0.5f * y * (1.0f + erff(y * 0.70710678118f));
      }
    }
  }
}

extern "C" void kernel_launch(void* const* d_in, const int* in_sizes, int n_in,
                              void* d_out, int out_size, void* d_ws, size_t ws_size,
                              hipStream_t stream) {
  const float* h     = (const float*)d_in[0];
  const int*   ei    = (const int*)d_in[1];
  const float* ew    = (const float*)d_in[2];
  const float* W     = (const float*)d_in[3];
  const float* b     = (const float*)d_in[4];
  const float* gamma = (const float*)d_in[5];
  const float* beta  = (const float*)d_in[6];

  const int n = in_sizes[0] / C;
  const int e = in_sizes[2];
  const int* src = ei;
  const int* dst = ei + e;

  float* out = (float*)d_out;

  // workspace layout (meta first for alignment)
  int2* meta   = (int2*)d_ws;                 // e int2
  float* deg   = (float*)(meta + e);          // n
  int* counts  = (int*)(deg + n);             // n
  int* rowptr  = counts + n;                  // n+1
  int* sums    = rowptr + (n + 1);            // <=256
  int* cursor  = sums + 256;                  // n
  unsigned short* Wb = (unsigned short*)(cursor + n);  // C*C bf16 (32 KB)
  float* agg   = out;                         // aggregate into output buffer

  const int nb = (n + SCAN_CHUNK - 1) / SCAN_CHUNK;

  k_prep    <<<C * C / 4 / 256, 256, 0, stream>>>(W, Wb);
  k_init    <<<(n + 255) / 256, 256, 0, stream>>>(deg, counts, n);
  k_edge_deg<<<(e + 255) / 256, 256, 0, stream>>>(dst, ew, deg, counts, e);
  k_dinv    <<<(n + 255) / 256, 256, 0, stream>>>(deg, n);

  k_scan1   <<<nb, 256, 0, stream>>>(counts, rowptr, sums, n);
  k_scan2   <<<1, 256, 0, stream>>>(sums, nb);
  k_scan3   <<<(n + 255) / 256, 256, 0, stream>>>(rowptr, sums, cursor, n, e);
  k_scatter <<<(e + 255) / 256, 256, 0, stream>>>(src, dst, ew, deg, cursor, meta, e);

  long gthreads = (long)n * 32;
  k_gather_agg<<<(int)((gthreads + 255) / 256), 256, 0, stream>>>(
      rowptr, meta, deg, h, agg, n);

  k_mfma_ln_gelu<<<(n + TM - 1) / TM, 256, 0, stream>>>(agg, h, Wb, b, gamma, beta, out, n);
}